// Round 7
// baseline (294.192 us; speedup 1.0000x reference)
//
#include <hip/hip_runtime.h>
#include <hip/hip_fp16.h>

#define NTOT 8192
#define NHALF 4096
#define DIM 256
#define LOG2E 1.4426950408889634f
#define LN2f 0.6931471805599453f
#define NEG_BIG -1e30f
#define COLSPLIT 16
#define BM 128
#define BN 64
#define CPB (NTOT / COLSPLIT)            /* 512 cols per block  */
#define NTILES (CPB / BN)                /* 8 tiles per block   */
#define NBLK ((NTOT / BM) * COLSPLIT)    /* 64 x 16 = 1024 blocks */

typedef _Float16 half8 __attribute__((ext_vector_type(8)));
typedef float floatx4 __attribute__((ext_vector_type(4)));

// ---------------- normalize: z1|z2 -> fp16 unit rows; re-arm counter ----------------
__global__ __launch_bounds__(256) void k_normalize(const float* __restrict__ z1,
                                                   const float* __restrict__ z2,
                                                   __half* __restrict__ zn,
                                                   unsigned int* __restrict__ cnt) {
  if (blockIdx.x == 0 && threadIdx.x == 0) *cnt = 0;
  int row = blockIdx.x * 4 + (threadIdx.x >> 6);
  int lane = threadIdx.x & 63;
  const float* src = (row < NHALF) ? (z1 + (size_t)row * DIM)
                                   : (z2 + (size_t)(row - NHALF) * DIM);
  float4 v = ((const float4*)src)[lane];
  float ss = v.x * v.x + v.y * v.y + v.z * v.z + v.w * v.w;
#pragma unroll
  for (int m = 1; m < 64; m <<= 1) ss += __shfl_xor(ss, m);
  float inv = 1.0f / fmaxf(sqrtf(ss), 1e-8f);
  __half2 h0, h1;
  h0.x = __float2half_rn(v.x * inv);
  h0.y = __float2half_rn(v.y * inv);
  h1.x = __float2half_rn(v.z * inv);
  h1.y = __float2half_rn(v.w * inv);
  __half2* dst = (__half2*)(zn + (size_t)row * DIM + lane * 4);
  dst[0] = h0;
  dst[1] = h1;
}

// ---------------- main S-pass: NO LDS staging, NO barriers in the hot loop ----------------
// grid = 64 rowTiles x 16 colSplits = 1024 blocks (4/CU), 256 threads.
// B fragments read directly from global (zn = 4MB, L2-resident; block tile L1-resident).
// 16 free-running waves/CU overlap MFMA / VALU / L1 across waves.
__global__ __launch_bounds__(256, 4) void k_main(
    const __half* __restrict__ zn, const float* __restrict__ logT,
    float* __restrict__ tS, float* __restrict__ pM, float* __restrict__ pL,
    unsigned int* __restrict__ cnt, float* __restrict__ out) {
  __shared__ float sred[512];  // tail reduce only
  __shared__ int lastFlag;

  const int bid = blockIdx.x;
  const int rowTile = bid >> 4;
  const int colq = bid & 15;
  const int rowBase = rowTile * BM;
  const int colBase = colq * CPB;
  const int tid = threadIdx.x;
  const int w = tid >> 6;
  const int lane = tid & 63;
  const int quad = lane >> 4;
  const int cl = lane & 15;

  const float invT = expf(-logT[0]);
  const float kk = invT * LOG2E;

  const int R0 = rowBase + w * 32;
  const int off = (R0 < NHALF) ? NHALF : -NHALF;
  const int T0 = R0 + off;  // this wave's 32 target cols: [T0, T0+32)

  // A fragments in registers: wave owns rows [R0, R0+32), 2 tiles of 16
  half8 a[2][8];
#pragma unroll
  for (int ks = 0; ks < 8; ks++) {
    a[0][ks] = *(const half8*)(zn + (size_t)(R0 + cl) * DIM + ks * 32 + quad * 8);
    a[1][ks] = *(const half8*)(zn + (size_t)(R0 + 16 + cl) * DIM + ks * 32 + quad * 8);
  }

  float Mx[8], L[8];
#pragma unroll
  for (int s = 0; s < 8; s++) { Mx[s] = NEG_BIG; L[s] = 0.f; }

  for (int t = 0; t < NTILES; t++) {
    const int colT = colBase + t * BN;
    // per-lane B base for this tile: row = colT + cl (+nt*16), 16B chunk = ks*4+quad
    const __half* bp = zn + (size_t)(colT + cl) * DIM + quad * 8;

    floatx4 acc[2][4];
#pragma unroll
    for (int rt = 0; rt < 2; rt++)
#pragma unroll
      for (int nt = 0; nt < 4; nt++) acc[rt][nt] = (floatx4){0.f, 0.f, 0.f, 0.f};

#pragma unroll
    for (int nt = 0; nt < 4; nt++) {
#pragma unroll
      for (int ks = 0; ks < 8; ks++) {
        // byte offset = nt*8192 + ks*64 : 4 bases + imm-folded ks offsets
        half8 b = *(const half8*)(bp + nt * 16 * DIM + ks * 32);
        acc[0][nt] = __builtin_amdgcn_mfma_f32_16x16x32_f16(a[0][ks], b, acc[0][nt], 0, 0, 0);
        acc[1][nt] = __builtin_amdgcn_mfma_f32_16x16x32_f16(a[1][ks], b, acc[1][nt], 0, 0, 0);
      }
    }

    // ---- straight-line update: unconditional diag mask + fixed-base softmax ----
    const int c0 = colT + cl;
#pragma unroll
    for (int rt = 0; rt < 2; rt++) {
#pragma unroll
      for (int r = 0; r < 4; r++) {
        const int s = rt * 4 + r;
        const int grow = R0 + rt * 16 + quad * 4 + r;
        float v0 = acc[rt][0][r], v1 = acc[rt][1][r];
        float v2 = acc[rt][2][r], v3 = acc[rt][3][r];
        v0 = (c0 == grow) ? NEG_BIG : v0;
        v1 = (c0 + 16 == grow) ? NEG_BIG : v1;
        v2 = (c0 + 32 == grow) ? NEG_BIG : v2;
        v3 = (c0 + 48 == grow) ? NEG_BIG : v3;  // exp2(v*kk) flushes to 0
        Mx[s] = fmaxf(fmaxf(Mx[s], fmaxf(v0, v1)), fmaxf(v2, v3));  // 2x v_max3
        L[s] += (exp2f(v0 * kk) + exp2f(v1 * kk)) + (exp2f(v2 * kk) + exp2f(v3 * kk));
      }
    }
    // rare wave-uniform capture of the exact MFMA target similarity
    if ((unsigned)(T0 - colT) < (unsigned)BN) {
#pragma unroll
      for (int rt = 0; rt < 2; rt++)
#pragma unroll
        for (int r = 0; r < 4; r++) {
          const int grow = R0 + rt * 16 + quad * 4 + r;
          const int tc = grow + off;
          if (c0 == tc) tS[grow] = acc[rt][0][r];
          if (c0 + 16 == tc) tS[grow] = acc[rt][1][r];
          if (c0 + 32 == tc) tS[grow] = acc[rt][2][r];
          if (c0 + 48 == tc) tS[grow] = acc[rt][3][r];
        }
    }
  }

  // combine 16 per-lane partials within each quad (pure max + add)
#pragma unroll
  for (int s = 0; s < 8; s++) {
    float m = Mx[s], l = L[s];
#pragma unroll
    for (int sh = 1; sh < 16; sh <<= 1) {
      m = fmaxf(m, __shfl_xor(m, sh));
      l += __shfl_xor(l, sh);
    }
    Mx[s] = m;
    L[s] = l;
  }
  if (cl == 0) {
#pragma unroll
    for (int rt = 0; rt < 2; rt++)
#pragma unroll
      for (int r = 0; r < 4; r++) {
        const int grow = R0 + rt * 16 + quad * 4 + r;
        const int s = rt * 4 + r;
        pM[colq * NTOT + grow] = Mx[s];   // coalesced partial layout
        pL[colq * NTOT + grow] = L[s];
      }
  }

  // ---- deadlock-free "last block reduces": never waits on co-residency ----
  __threadfence();
  __syncthreads();
  if (tid == 0) {
    unsigned prev = __hip_atomic_fetch_add(cnt, 1u, __ATOMIC_ACQ_REL,
                                           __HIP_MEMORY_SCOPE_AGENT);
    lastFlag = (prev == (unsigned)(NBLK - 1)) ? 1 : 0;
  }
  __syncthreads();
  if (!lastFlag) return;

  // final reduce over col-splits, vectorized float4 (8192 rows / 256 thr / 4)
  const float4* pM4 = (const float4*)pM;
  const float4* pL4 = (const float4*)pL;
  const float4* tS4 = (const float4*)tS;
  float lossSum = 0.f, corrSum = 0.f;
  for (int it = 0; it < NTOT / (256 * 4); it++) {
    const int r4 = it * 256 + tid;  // float4 index; rows 4*r4..4*r4+3
    float4 m = make_float4(NEG_BIG, NEG_BIG, NEG_BIG, NEG_BIG);
    float4 Ls = make_float4(0.f, 0.f, 0.f, 0.f);
#pragma unroll
    for (int q = 0; q < COLSPLIT; q++) {
      float4 mq = pM4[q * (NTOT / 4) + r4];
      float4 lq = pL4[q * (NTOT / 4) + r4];
      m.x = fmaxf(m.x, mq.x); m.y = fmaxf(m.y, mq.y);
      m.z = fmaxf(m.z, mq.z); m.w = fmaxf(m.w, mq.w);
      Ls.x += lq.x; Ls.y += lq.y; Ls.z += lq.z; Ls.w += lq.w;
    }
    float4 tp = tS4[r4];
    lossSum += (LN2f * log2f(Ls.x) - tp.x * invT) +
               (LN2f * log2f(Ls.y) - tp.y * invT) +
               (LN2f * log2f(Ls.z) - tp.z * invT) +
               (LN2f * log2f(Ls.w) - tp.w * invT);
    corrSum += ((tp.x >= m.x) ? 1.f : 0.f) + ((tp.y >= m.y) ? 1.f : 0.f) +
               ((tp.z >= m.z) ? 1.f : 0.f) + ((tp.w >= m.w) ? 1.f : 0.f);
  }
  float* sl = sred;
  float* sc = sred + 256;
  sl[tid] = lossSum;
  sc[tid] = corrSum;
  __syncthreads();
  for (int s2 = 128; s2 > 0; s2 >>= 1) {
    if (tid < s2) { sl[tid] += sl[tid + s2]; sc[tid] += sc[tid + s2]; }
    __syncthreads();
  }
  if (tid == 0) {
    out[0] = sl[0] * (1.0f / (float)NTOT);
    out[1] = sc[0] * 0.5f;
  }
}

extern "C" void kernel_launch(void* const* d_in, const int* in_sizes, int n_in,
                              void* d_out, int out_size, void* d_ws, size_t ws_size,
                              hipStream_t stream) {
  const float* z1 = (const float*)d_in[0];
  const float* z2 = (const float*)d_in[1];
  const float* logT = (const float*)d_in[2];

  // workspace layout (~5.07 MB)
  char* ws = (char*)d_ws;
  __half* zn = (__half*)ws;                                   // 4 MB unit rows
  float* tS = (float*)(ws + (size_t)(4 << 20));               // 32 KB target sims
  float* pM = (float*)(ws + (size_t)(4 << 20) + (32 << 10));  // 512 KB (16 splits)
  float* pL = pM + COLSPLIT * NTOT;                           // 512 KB
  unsigned int* cnt = (unsigned int*)(pL + COLSPLIT * NTOT);  // 4 B

  k_normalize<<<NTOT / 4, 256, 0, stream>>>(z1, z2, zn, cnt);
  k_main<<<NBLK, 256, 0, stream>>>(zn, logT, tS, pM, pL, cnt, (float*)d_out);
}

// Round 8
// 172.729 us; speedup vs baseline: 1.7032x; 1.7032x over previous
//
#include <hip/hip_runtime.h>
#include <hip/hip_fp16.h>

#define NTOT 8192
#define NHALF 4096
#define DIM 256
#define LOG2E 1.4426950408889634f
#define LN2f 0.6931471805599453f
#define NEG_BIG -1e30f
#define COLSPLIT 16                       /* partial splits = col blocks */
#define CPB (NTOT / COLSPLIT)             /* 512 cols per block */
#define SUBC 128                          /* cols per LDS sub-tile */
#define NSUB (CPB / SUBC)                 /* 4 sub-tiles */
#define RS 32                             /* row splits */
#define RPB (NTOT / RS)                   /* 256 rows per block */
#define NBLK (COLSPLIT * RS)              /* 512 blocks */
#define REDBLK 8

typedef _Float16 half8 __attribute__((ext_vector_type(8)));
typedef float floatx4 __attribute__((ext_vector_type(4)));

// ---------------- normalize: z1|z2 -> fp16 unit rows; re-arm counter ----------------
__global__ __launch_bounds__(256) void k_normalize(const float* __restrict__ z1,
                                                   const float* __restrict__ z2,
                                                   __half* __restrict__ zn,
                                                   unsigned int* __restrict__ cnt2) {
  if (blockIdx.x == 0 && threadIdx.x == 0) *cnt2 = 0;
  int row = blockIdx.x * 4 + (threadIdx.x >> 6);
  int lane = threadIdx.x & 63;
  const float* src = (row < NHALF) ? (z1 + (size_t)row * DIM)
                                   : (z2 + (size_t)(row - NHALF) * DIM);
  float4 v = ((const float4*)src)[lane];
  float ss = v.x * v.x + v.y * v.y + v.z * v.z + v.w * v.w;
#pragma unroll
  for (int m = 1; m < 64; m <<= 1) ss += __shfl_xor(ss, m);
  float inv = 1.0f / fmaxf(sqrtf(ss), 1e-8f);
  __half2 h0, h1;
  h0.x = __float2half_rn(v.x * inv);
  h0.y = __float2half_rn(v.y * inv);
  h1.x = __float2half_rn(v.z * inv);
  h1.y = __float2half_rn(v.w * inv);
  __half2* dst = (__half2*)(zn + (size_t)row * DIM + lane * 4);
  dst[0] = h0;
  dst[1] = h1;
}

// ---------------- main S-pass: B sub-tile resident in LDS, barrier-free hot loop ----
// grid = 16 colBlocks x 32 rowSplits = 512 blocks (2/CU), 256 threads (4 waves).
// Block covers 512 cols x 256 rows. 4 sub-tiles of 128 cols; per sub-tile the
// 4 waves free-run over 2x128 rows with NO barriers (B is read-only in LDS).
__global__ __launch_bounds__(256, 2) void k_main(
    const __half* __restrict__ zn, const float* __restrict__ logT,
    float* __restrict__ tS, float* __restrict__ pM, float* __restrict__ pL) {
  __shared__ uint4 ldsB[SUBC * 32];  // 128 cols x 512B = 64 KB, xor-swizzled

  const int bid = blockIdx.x;
  const int cb = bid >> 5;        // col block 0..15
  const int rs = bid & 31;        // row split 0..31
  const int rowBase = rs * RPB;   // 256-row slab
  const int colBase = cb * CPB;   // 512-col slab
  const int tid = threadIdx.x;
  const int w = tid >> 6;
  const int lane = tid & 63;
  const int quad = lane >> 4;
  const int cl = lane & 15;

  const float invT = expf(-logT[0]);
  const float kk = invT * LOG2E;

  // B staging geometry (verified pattern): thread covers ch = tid&31 of col0+8i
  const int ch = tid & 31;
  const int col0 = tid >> 5;
  const int ldsW = col0 * 32 + (ch ^ (col0 & 7));  // + i*256 per chunk

  float Mx[16], L[16];
#pragma unroll
  for (int s = 0; s < 16; s++) { Mx[s] = NEG_BIG; L[s] = 0.f; }

  for (int sub = 0; sub < NSUB; sub++) {
    const int colS = colBase + sub * SUBC;
    __syncthreads();  // previous sub-tile's readers done
#pragma unroll
    for (int i = 0; i < 16; i++) {
      uint4 v = *(const uint4*)(zn + (size_t)(colS + col0 + i * 8) * DIM + ch * 8);
      ldsB[ldsW + i * 256] = v;
    }
    __syncthreads();  // B sub-tile visible

#pragma unroll
    for (int it2 = 0; it2 < 2; it2++) {
      const int R0 = rowBase + it2 * 128 + w * 32;
      const int off = (R0 < NHALF) ? NHALF : -NHALF;
      const int T0 = R0 + off;

      // A fragments for this 32-row slab (from L2-resident zn)
      half8 a[2][8];
#pragma unroll
      for (int ks = 0; ks < 8; ks++) {
        a[0][ks] = *(const half8*)(zn + (size_t)(R0 + cl) * DIM + ks * 32 + quad * 8);
        a[1][ks] = *(const half8*)(zn + (size_t)(R0 + 16 + cl) * DIM + ks * 32 + quad * 8);
      }

      floatx4 acc[2][8];
#pragma unroll
      for (int rt = 0; rt < 2; rt++)
#pragma unroll
        for (int nt = 0; nt < 8; nt++) acc[rt][nt] = (floatx4){0.f, 0.f, 0.f, 0.f};

#pragma unroll
      for (int nt = 0; nt < 8; nt++) {
        const int bc = nt * 16 + cl;
#pragma unroll
        for (int ks = 0; ks < 8; ks++) {
          const int kc = ks * 4 + quad;
          half8 b = *(const half8*)&ldsB[bc * 32 + (kc ^ (bc & 7))];
          acc[0][nt] = __builtin_amdgcn_mfma_f32_16x16x32_f16(a[0][ks], b, acc[0][nt], 0, 0, 0);
          acc[1][nt] = __builtin_amdgcn_mfma_f32_16x16x32_f16(a[1][ks], b, acc[1][nt], 0, 0, 0);
        }
      }

      // straight-line update: diag mask + fixed-base softmax (L += 2^(v*kk))
#pragma unroll
      for (int rt = 0; rt < 2; rt++) {
#pragma unroll
        for (int r = 0; r < 4; r++) {
          const int s = it2 * 8 + rt * 4 + r;
          const int grow = R0 + rt * 16 + quad * 4 + r;
          float mx = Mx[s], l = L[s];
#pragma unroll
          for (int nt = 0; nt < 8; nt++) {
            const int col = colS + nt * 16 + cl;
            float v = acc[rt][nt][r];
            v = (col == grow) ? NEG_BIG : v;  // exp2(v*kk) flushes to 0
            mx = fmaxf(mx, v);
            l += exp2f(v * kk);
          }
          Mx[s] = mx;
          L[s] = l;
        }
      }
      // rare wave-uniform capture of the exact MFMA target similarity
      if ((unsigned)(T0 - colS) < (unsigned)SUBC) {
#pragma unroll
        for (int rt = 0; rt < 2; rt++)
#pragma unroll
          for (int r = 0; r < 4; r++) {
            const int grow = R0 + rt * 16 + quad * 4 + r;
            const int tc = grow + off;
#pragma unroll
            for (int nt = 0; nt < 8; nt++)
              if (colS + nt * 16 + cl == tc) tS[grow] = acc[rt][nt][r];
          }
      }
    }
  }

  // combine 16 per-lane partials within each quad (pure max + add)
#pragma unroll
  for (int s = 0; s < 16; s++) {
    float m = Mx[s], l = L[s];
#pragma unroll
    for (int sh = 1; sh < 16; sh <<= 1) {
      m = fmaxf(m, __shfl_xor(m, sh));
      l += __shfl_xor(l, sh);
    }
    Mx[s] = m;
    L[s] = l;
  }
  if (cl == 0) {
#pragma unroll
    for (int it2 = 0; it2 < 2; it2++)
#pragma unroll
      for (int rt = 0; rt < 2; rt++)
#pragma unroll
        for (int r = 0; r < 4; r++) {
          const int grow = rowBase + it2 * 128 + w * 32 + rt * 16 + quad * 4 + r;
          const int s = it2 * 8 + rt * 4 + r;
          pM[cb * NTOT + grow] = Mx[s];
          pL[cb * NTOT + grow] = L[s];
        }
  }
}

// ---------------- final reduce: 8 parallel blocks + last-block finalize ----------------
__global__ __launch_bounds__(256) void k_reduce(const float* __restrict__ pM,
                                                const float* __restrict__ pL,
                                                const float* __restrict__ tS,
                                                const float* __restrict__ logT,
                                                float* __restrict__ pPart,
                                                unsigned int* __restrict__ cnt2,
                                                float* __restrict__ out) {
  __shared__ float sred[512];
  __shared__ int lastFlag;
  const int tid = threadIdx.x;
  const float invT = expf(-logT[0]);

  const float4* pM4 = (const float4*)pM;
  const float4* pL4 = (const float4*)pL;
  const float4* tS4 = (const float4*)tS;
  const int r4 = blockIdx.x * 256 + tid;  // float4-row index, 0..2047
  float4 m = make_float4(NEG_BIG, NEG_BIG, NEG_BIG, NEG_BIG);
  float4 Ls = make_float4(0.f, 0.f, 0.f, 0.f);
#pragma unroll
  for (int q = 0; q < COLSPLIT; q++) {
    float4 mq = pM4[q * (NTOT / 4) + r4];
    float4 lq = pL4[q * (NTOT / 4) + r4];
    m.x = fmaxf(m.x, mq.x); m.y = fmaxf(m.y, mq.y);
    m.z = fmaxf(m.z, mq.z); m.w = fmaxf(m.w, mq.w);
    Ls.x += lq.x; Ls.y += lq.y; Ls.z += lq.z; Ls.w += lq.w;
  }
  float4 tp = tS4[r4];
  float lossSum = (LN2f * log2f(Ls.x) - tp.x * invT) +
                  (LN2f * log2f(Ls.y) - tp.y * invT) +
                  (LN2f * log2f(Ls.z) - tp.z * invT) +
                  (LN2f * log2f(Ls.w) - tp.w * invT);
  float corrSum = ((tp.x >= m.x) ? 1.f : 0.f) + ((tp.y >= m.y) ? 1.f : 0.f) +
                  ((tp.z >= m.z) ? 1.f : 0.f) + ((tp.w >= m.w) ? 1.f : 0.f);

  float* sl = sred;
  float* sc = sred + 256;
  sl[tid] = lossSum;
  sc[tid] = corrSum;
  __syncthreads();
  for (int s2 = 128; s2 > 0; s2 >>= 1) {
    if (tid < s2) { sl[tid] += sl[tid + s2]; sc[tid] += sc[tid + s2]; }
    __syncthreads();
  }
  if (tid == 0) {
    pPart[blockIdx.x * 2 + 0] = sl[0];
    pPart[blockIdx.x * 2 + 1] = sc[0];
  }
  __threadfence();
  __syncthreads();
  if (tid == 0) {
    unsigned prev = __hip_atomic_fetch_add(cnt2, 1u, __ATOMIC_ACQ_REL,
                                           __HIP_MEMORY_SCOPE_AGENT);
    lastFlag = (prev == (unsigned)(REDBLK - 1)) ? 1 : 0;
  }
  __syncthreads();
  if (!lastFlag) return;
  if (tid == 0) {
    float tl = 0.f, tc = 0.f;
#pragma unroll
    for (int b = 0; b < REDBLK; b++) { tl += pPart[b * 2]; tc += pPart[b * 2 + 1]; }
    out[0] = tl * (1.0f / (float)NTOT);
    out[1] = tc * 0.5f;
  }
}

extern "C" void kernel_launch(void* const* d_in, const int* in_sizes, int n_in,
                              void* d_out, int out_size, void* d_ws, size_t ws_size,
                              hipStream_t stream) {
  const float* z1 = (const float*)d_in[0];
  const float* z2 = (const float*)d_in[1];
  const float* logT = (const float*)d_in[2];

  // workspace layout (~5.07 MB, == R7-proven footprint)
  char* ws = (char*)d_ws;
  __half* zn = (__half*)ws;                                   // 4 MB unit rows
  float* tS = (float*)(ws + (size_t)(4 << 20));               // 32 KB target sims
  float* pM = (float*)(ws + (size_t)(4 << 20) + (32 << 10));  // 512 KB
  float* pL = pM + COLSPLIT * NTOT;                           // 512 KB
  float* pPart = pL + COLSPLIT * NTOT;                        // 64 B
  unsigned int* cnt2 = (unsigned int*)(pPart + 2 * REDBLK);   // 4 B

  k_normalize<<<NTOT / 4, 256, 0, stream>>>(z1, z2, zn, cnt2);
  k_main<<<NBLK, 256, 0, stream>>>(zn, logT, tS, pM, pL);
  k_reduce<<<REDBLK, 256, 0, stream>>>(pM, pL, tS, logT, pPart, cnt2, (float*)d_out);
}